// Round 8
// baseline (369.140 us; speedup 1.0000x reference)
//
#include <hip/hip_runtime.h>
#include <stdint.h>

#define NTOK 197
#define HD 64
#define NH 12
#define CDIM 768
#define BB 64
#define MTOT (BB*NTOK)      /* 12608 */
#define MPAD 12672          /* 99*128 */
#define SCALE 0.125f

typedef __attribute__((ext_vector_type(8))) short short8;
typedef __attribute__((ext_vector_type(4))) float f32x4;
typedef unsigned short us;

__device__ __forceinline__ us f2b(float f){
    union { float f; uint32_t u; } v; v.f = f;
    uint32_t u = v.u;
    uint32_t r = u + 0x7fffu + ((u >> 16) & 1u);
    return (us)(r >> 16);
}

// ---------------- prep ----------------
__global__ void cvt_kernel(const float* __restrict__ in, us* __restrict__ out, int n4){
    int i = blockIdx.x*blockDim.x + threadIdx.x;
    if (i < n4){
        float4 v = ((const float4*)in)[i];
        ushort4 o;
        o.x = f2b(v.x); o.y = f2b(v.y); o.z = f2b(v.z); o.w = f2b(v.w);
        ((ushort4*)out)[i] = o;
    }
}

__global__ void bias_kernel(const int* __restrict__ rel_index, const float* __restrict__ rel_table,
                            float* __restrict__ biasm){
    int i = blockIdx.x*blockDim.x + threadIdx.x;
    if (i < NTOK*NTOK){
        int idx = rel_index[i];
        #pragma unroll
        for (int h = 0; h < NH; ++h)
            biasm[h*NTOK*NTOK + i] = rel_table[idx*NH + h];
    }
}

// ============ flat GEMM: NO LDS, NO barriers. BM=128, BN=256, 8 waves. ============
// Direct global->VGPR fragment loads (A,B both row-major (rows,K)); 2-deep manual
// frag double-buffer, fully unrolled K (compile-time imm offsets, ~zero loop VALU).
// XCD-chunked y-fastest dispatch decode (A-panel sharing).
// EPI==0: scatter Q/K/V + bias/scale fold. EPI==1: fp32 out + proj_b.
template<int EPI>
__global__ __launch_bounds__(512) void flat_gemm_kernel(
    const us* __restrict__ A, const us* __restrict__ Bw,
    float* __restrict__ Cout, us* __restrict__ Qo, us* __restrict__ Ko, us* __restrict__ Vo,
    const float* __restrict__ b0, const float* __restrict__ b2, int ny)
{
    const int tid  = threadIdx.x;
    const int lane = tid & 63;
    const int wave = tid >> 6;
    const int wrr = wave >> 2;          // 0..1: M half (64 rows)
    const int wcc = wave & 3;           // 0..3: N band (64 cols)
    const int lr = lane & 15;
    const int g  = lane >> 4;

    // bijective XCD-chunked decode, y-fastest (col-blocks share an A panel)
    const int NB   = gridDim.x;
    const int base = NB >> 3;
    const int rem  = NB & 7;
    const int id   = blockIdx.x;
    const int xcd  = id & 7;
    const int qq   = id >> 3;
    const int start = (xcd < rem) ? xcd*(base+1) : rem*(base+1) + (xcd-rem)*base;
    const int w    = start + qq;
    const int bx   = w / ny;
    const int by   = w - bx*ny;
    const int m0 = bx * 128;
    const int n0 = by * 256;

    f32x4 acc[4][4];
    #pragma unroll
    for (int i=0;i<4;i++)
        #pragma unroll
        for (int j=0;j<4;j++) acc[i][j] = (f32x4){0.f,0.f,0.f,0.f};

    // fragment base pointers: row = tile row + lr, k-offset = g*8
    const us* aP[4];
    const us* bP[4];
    #pragma unroll
    for (int mt=0;mt<4;mt++) aP[mt] = A  + (size_t)(m0 + wrr*64 + mt*16 + lr)*CDIM + g*8;
    #pragma unroll
    for (int nt=0;nt<4;nt++) bP[nt] = Bw + (size_t)(n0 + wcc*64 + nt*16 + lr)*CDIM + g*8;

    short8 fa0[4], fb0[4], fa1[4], fb1[4];

    #define LDF(da, db, kt) do{ \
        _Pragma("unroll") for (int mt=0;mt<4;mt++) da[mt] = *(const short8*)(aP[mt] + (kt)*32); \
        _Pragma("unroll") for (int nt=0;nt<4;nt++) db[nt] = *(const short8*)(bP[nt] + (kt)*32); \
    }while(0)
    #define FMA(sa, sb) do{ \
        _Pragma("unroll") for (int mt=0;mt<4;mt++) \
            _Pragma("unroll") for (int nt=0;nt<4;nt++) \
                acc[mt][nt] = __builtin_amdgcn_mfma_f32_16x16x32_bf16(sa[mt], sb[nt], acc[mt][nt], 0,0,0); \
    }while(0)

    LDF(fa0, fb0, 0);
    #pragma unroll
    for (int it = 0; it < 12; ++it){
        LDF(fa1, fb1, 2*it+1);
        FMA(fa0, fb0);
        if (it < 11) LDF(fa0, fb0, 2*it+2);
        FMA(fa1, fb1);
    }
    #undef LDF
    #undef FMA

    #pragma unroll
    for (int mt=0;mt<4;mt++){
        #pragma unroll
        for (int r=0;r<4;r++){
            int m = m0 + wrr*64 + mt*16 + g*4 + r;
            if (m >= MTOT) continue;
            if (EPI == 1){
                #pragma unroll
                for (int nt=0;nt<4;nt++){
                    int n = n0 + wcc*64 + nt*16 + lr;
                    Cout[(size_t)m*CDIM + n] = acc[mt][nt][r] + b0[n];
                }
            } else {
                int bidx = m / NTOK;
                int tok  = m - bidx*NTOK;
                #pragma unroll
                for (int nt=0;nt<4;nt++){
                    int n = n0 + wcc*64 + nt*16 + lr;
                    int which = (n >= 1536) ? 2 : (n >= 768 ? 1 : 0);
                    int hn = n - which*CDIM;
                    int h = hn >> 6, d = hn & 63;
                    size_t off = ((size_t)((bidx*NH + h)*NTOK + tok))*HD + d;
                    float v = acc[mt][nt][r];
                    if (which == 0)      Qo[off] = f2b((v + b0[hn]) * SCALE);
                    else if (which == 1) Ko[off] = f2b(v);
                    else                 Vo[off] = f2b(v + b2[hn]);
                }
            }
        }
    }
}

// ---------------- fused attention: one block per (b,h) ----------------
__global__ __launch_bounds__(256) void attn_kernel(
    const us* __restrict__ Q,
    const us* __restrict__ K,
    const us* __restrict__ V,
    const float* __restrict__ biasm,
    us* __restrict__ Ao)
{
    __shared__ us Vt[64][232];
    __shared__ us Ps[4][16][232];
    const int bh = blockIdx.x;
    const int b = bh / NH;
    const int h = bh - b*NH;
    const us* Qh = Q + (size_t)bh*NTOK*HD;
    const us* Kh = K + (size_t)bh*NTOK*HD;
    const us* Vh = V + (size_t)bh*NTOK*HD;
    const float* bh_bias = biasm + (size_t)h*NTOK*NTOK;
    const int tid = threadIdx.x, lane = tid & 63, wave = tid >> 6;
    const int lr = lane & 15, g = lane >> 4, ko = g*8;

    for (int i = tid; i < 64*232/2; i += 256) ((uint32_t*)Vt)[i] = 0;
    __syncthreads();
    {
        int d0 = (tid & 7) * 8;
        for (int t = tid >> 3; t < NTOK; t += 32){
            short8 v = *(const short8*)&Vh[t*HD + d0];
            #pragma unroll
            for (int j=0;j<8;j++) Vt[d0+j][t] = (us)v[j];
        }
    }
    __syncthreads();

    for (int s = wave; s < 13; s += 4){
        int qrow = s*16 + lr; qrow = qrow > 196 ? 196 : qrow;
        short8 qa0 = *(const short8*)&Qh[qrow*HD + ko];
        short8 qa1 = *(const short8*)&Qh[qrow*HD + 32 + ko];
        f32x4 S[13];
        #pragma unroll
        for (int t=0;t<13;t++){
            int kc = t*16 + lr; kc = kc > 196 ? 196 : kc;
            short8 kb0 = *(const short8*)&Kh[kc*HD + ko];
            short8 kb1 = *(const short8*)&Kh[kc*HD + 32 + ko];
            f32x4 a = (f32x4){0.f,0.f,0.f,0.f};
            a = __builtin_amdgcn_mfma_f32_16x16x32_bf16(qa0, kb0, a, 0,0,0);
            a = __builtin_amdgcn_mfma_f32_16x16x32_bf16(qa1, kb1, a, 0,0,0);
            S[t] = a;
        }
        float rmax[4] = {-3e38f,-3e38f,-3e38f,-3e38f};
        #pragma unroll
        for (int t=0;t<13;t++){
            int col = t*16 + lr;
            bool cok = col < NTOK;
            int colc = cok ? col : 196;
            #pragma unroll
            for (int r=0;r<4;r++){
                int row = s*16 + g*4 + r; row = row > 196 ? 196 : row;
                float xv = S[t][r] + bh_bias[row*NTOK + colc];
                xv = cok ? xv : -1e30f;
                S[t][r] = xv;
                rmax[r] = fmaxf(rmax[r], xv);
            }
        }
        #pragma unroll
        for (int r=0;r<4;r++)
            #pragma unroll
            for (int msk=1; msk<16; msk<<=1)
                rmax[r] = fmaxf(rmax[r], __shfl_xor(rmax[r], msk));
        float rsum[4] = {0.f,0.f,0.f,0.f};
        #pragma unroll
        for (int t=0;t<13;t++)
            #pragma unroll
            for (int r=0;r<4;r++){
                float e = __expf(S[t][r] - rmax[r]);
                S[t][r] = e;
                rsum[r] += e;
            }
        #pragma unroll
        for (int r=0;r<4;r++){
            #pragma unroll
            for (int msk=1; msk<16; msk<<=1)
                rsum[r] += __shfl_xor(rsum[r], msk);
            rsum[r] = 1.f / rsum[r];
        }
        #pragma unroll
        for (int t=0;t<13;t++)
            #pragma unroll
            for (int r=0;r<4;r++)
                Ps[wave][g*4+r][t*16+lr] = f2b(S[t][r] * rsum[r]);
        #pragma unroll
        for (int r=0;r<4;r++) Ps[wave][g*4+r][208+lr] = 0;
        asm volatile("s_waitcnt lgkmcnt(0)" ::: "memory");
        f32x4 pv[4];
        #pragma unroll
        for (int nt=0;nt<4;nt++) pv[nt] = (f32x4){0.f,0.f,0.f,0.f};
        #pragma unroll
        for (int ks=0; ks<7; ks++){
            int k0 = ks*32 + ko;
            short8 pa = *(const short8*)&Ps[wave][lr][k0];
            #pragma unroll
            for (int nt=0;nt<4;nt++){
                short8 vb = *(const short8*)&Vt[nt*16+lr][k0];
                pv[nt] = __builtin_amdgcn_mfma_f32_16x16x32_bf16(pa, vb, pv[nt], 0,0,0);
            }
        }
        #pragma unroll
        for (int nt=0;nt<4;nt++)
            #pragma unroll
            for (int r=0;r<4;r++){
                int tok = s*16 + g*4 + r;
                if (tok < NTOK)
                    Ao[(size_t)(b*NTOK + tok)*CDIM + h*HD + nt*16 + lr] = f2b(pv[nt][r]);
            }
    }
}

extern "C" void kernel_launch(void* const* d_in, const int* in_sizes, int n_in,
                              void* d_out, int out_size, void* d_ws, size_t ws_size,
                              hipStream_t stream)
{
    const float* x        = (const float*)d_in[0];
    const float* qkv_w    = (const float*)d_in[1];
    const float* q_bias   = (const float*)d_in[2];
    const float* v_bias   = (const float*)d_in[3];
    const float* rel_tab  = (const float*)d_in[4];
    const float* proj_w   = (const float*)d_in[5];
    const float* proj_b   = (const float*)d_in[6];
    const int*   rel_idx  = (const int*)d_in[7];
    float* out = (float*)d_out;

    char* w = (char*)d_ws;
    us* xb    = (us*)w; w += (size_t)MPAD*CDIM*2;
    us* wqkv  = (us*)w; w += (size_t)3*CDIM*CDIM*2;
    us* wproj = (us*)w; w += (size_t)CDIM*CDIM*2;
    us* Qb    = (us*)w; w += (size_t)BB*NH*NTOK*HD*2;
    us* Kb    = (us*)w; w += (size_t)BB*NH*NTOK*HD*2;
    us* Vb    = (us*)w; w += (size_t)BB*NH*NTOK*HD*2;
    float* biasm = (float*)w; w += (size_t)NH*NTOK*NTOK*4;
    us* aob   = (us*)w; w += (size_t)MPAD*CDIM*2;

    int n1 = MTOT*CDIM/4;
    cvt_kernel<<<(n1+255)/256, 256, 0, stream>>>(x, xb, n1);
    int n2 = 3*CDIM*CDIM/4;
    cvt_kernel<<<(n2+255)/256, 256, 0, stream>>>(qkv_w, wqkv, n2);
    int n3 = CDIM*CDIM/4;
    cvt_kernel<<<(n3+255)/256, 256, 0, stream>>>(proj_w, wproj, n3);
    bias_kernel<<<(NTOK*NTOK+255)/256, 256, 0, stream>>>(rel_idx, rel_tab, biasm);

    // QKV: M=12608(->12672 pad), N=2304, K=768. 99 x 9 blocks.
    flat_gemm_kernel<0><<<99*9, 512, 0, stream>>>(xb, wqkv, nullptr, Qb, Kb, Vb, q_bias, v_bias, 9);
    attn_kernel<<<BB*NH, 256, 0, stream>>>(Qb, Kb, Vb, biasm, aob);
    // proj: N=768. 99 x 3 blocks.
    flat_gemm_kernel<1><<<99*3, 512, 0, stream>>>(aob, wproj, out, nullptr, nullptr, nullptr, proj_b, nullptr, 3);
}

// Round 9
// 176.502 us; speedup vs baseline: 2.0914x; 2.0914x over previous
//
#include <hip/hip_runtime.h>
#include <stdint.h>

#define NTOK 197
#define HD 64
#define NH 12
#define CDIM 768
#define BB 64
#define MTOT (BB*NTOK)      /* 12608 */
#define MPAD 12672          /* 99*128 */
#define SCALE 0.125f

typedef __attribute__((ext_vector_type(8))) short short8;
typedef __attribute__((ext_vector_type(4))) float f32x4;
typedef unsigned short us;

__device__ __forceinline__ us f2b(float f){
    union { float f; uint32_t u; } v; v.f = f;
    uint32_t u = v.u;
    uint32_t r = u + 0x7fffu + ((u >> 16) & 1u);
    return (us)(r >> 16);
}

__device__ __forceinline__ float b2f(us b){
    union { uint32_t u; float f; } v; v.u = ((uint32_t)b) << 16;
    return v.f;
}

__device__ __forceinline__ void gload16(const us* g, us* l){
    __builtin_amdgcn_global_load_lds((const __attribute__((address_space(1))) void*)g,
                                     (__attribute__((address_space(3))) void*)l, 16, 0, 0);
}

// ---------------- prep ----------------
__global__ void cvt_kernel(const float* __restrict__ in, us* __restrict__ out, int n4){
    int i = blockIdx.x*blockDim.x + threadIdx.x;
    if (i < n4){
        float4 v = ((const float4*)in)[i];
        ushort4 o;
        o.x = f2b(v.x); o.y = f2b(v.y); o.z = f2b(v.z); o.w = f2b(v.w);
        ((ushort4*)out)[i] = o;
    }
}

__global__ void bias_kernel(const int* __restrict__ rel_index, const float* __restrict__ rel_table,
                            float* __restrict__ biasm){
    int i = blockIdx.x*blockDim.x + threadIdx.x;
    if (i < NTOK*NTOK){
        int idx = rel_index[i];
        #pragma unroll
        for (int h = 0; h < NH; ++h)
            biasm[h*NTOK*NTOK + i] = rel_table[idx*NH + h];
    }
}

// ============ persistent GEMM: BM=BN=BK=128, 4 waves, TPB tiles/block ============
// Inner K-loop identical to R6 (refcheck-passed). New: persistent tile loop +
// packed epilogue (bias-folded bf16 C -> LDS stride-132 transpose -> 16B stores).
// EPI==0: scatter to Q/K/V (which is tile-uniform). EPI==1: fp32 out + proj_b.
template<int EPI, int TPB>
__global__ __launch_bounds__(256) void pgemm_kernel(
    const us* __restrict__ A, const us* __restrict__ Bw,
    float* __restrict__ Cout, us* __restrict__ Qo, us* __restrict__ Ko, us* __restrict__ Vo,
    const float* __restrict__ b0, const float* __restrict__ b2, int ny)
{
    __shared__ __align__(16) us lds[32768];   // As=[0,16384), Bs=[16384,32768); cbuf aliases all
    us* As = lds;
    us* Bs = lds + 16384;
    const int tid  = threadIdx.x;
    const int lane = tid & 63;
    const int wave = tid >> 6;
    const int wr = wave >> 1, wc = wave & 1;
    const int lr = lane & 15;
    const int g  = lane >> 4;

    // bijective XCD-chunked decode on block id; block handles tiles w0..w0+TPB-1
    const int NB   = gridDim.x;
    const int base = NB >> 3;
    const int rem  = NB & 7;
    const int id   = blockIdx.x;
    const int xcd  = id & 7;
    const int qq   = id >> 3;
    const int start = (xcd < rem) ? xcd*(base+1) : rem*(base+1) + (xcd-rem)*base;
    const int w0   = (start + qq) * TPB;

    const int row0 = tid >> 4;          // staging row (mod 16)
    const int cg   = (tid & 15) ^ row0; // pre-swizzled source chunk
    const int NT   = CDIM / 128;        // 6 K-steps

    #pragma unroll 1
    for (int tt = 0; tt < TPB; ++tt){
        const int w  = w0 + tt;
        const int bx = w / ny;
        const int by = w - bx*ny;
        const int m0 = bx * 128;
        const int n0 = by * 128;
        const int which = (EPI == 0) ? (n0 >> 9) / ((768*2) >> 10) : 0; // n0/768, tile-uniform
        const int whc = (EPI == 0) ? (n0 / CDIM) : 0;

        // per-thread column bias/scale fold values (4 nt columns)
        float addf[4], sclf[4];
        #pragma unroll
        for (int nt=0;nt<4;nt++){
            int n = n0 + wc*64 + nt*16 + lr;
            if (EPI == 1){ addf[nt] = b0[n]; sclf[nt] = 1.f; }
            else {
                int hn = n - whc*CDIM;
                if (whc == 0){ addf[nt] = b0[hn]; sclf[nt] = SCALE; }
                else if (whc == 1){ addf[nt] = 0.f; sclf[nt] = 1.f; }
                else { addf[nt] = b2[hn]; sclf[nt] = 1.f; }
            }
        }

        f32x4 acc[4][4];
        #pragma unroll
        for (int i=0;i<4;i++)
            #pragma unroll
            for (int j=0;j<4;j++) acc[i][j] = (f32x4){0.f,0.f,0.f,0.f};

        const us* gA = A  + (size_t)(m0 + row0)*CDIM + cg*8;
        const us* gB = Bw + (size_t)(n0 + row0)*CDIM + cg*8;

        #pragma unroll 1
        for (int kt = 0; kt < NT; ++kt){
            __syncthreads();
            #pragma unroll
            for (int j=0;j<8;j++){
                gload16(gA + (size_t)j*16*CDIM + kt*128, As + tid*8 + j*2048);
                gload16(gB + (size_t)j*16*CDIM + kt*128, Bs + tid*8 + j*2048);
            }
            __syncthreads();
            #pragma unroll
            for (int kk=0; kk<4; ++kk){
                const int co = 8*((kk*4 + g) ^ lr);
                short8 af[4], bf[4];
                #pragma unroll
                for (int mt=0;mt<4;mt++)
                    af[mt] = *(const short8*)&As[(wr*64+mt*16+lr)*128 + co];
                #pragma unroll
                for (int nt=0;nt<4;nt++)
                    bf[nt] = *(const short8*)&Bs[(wc*64+nt*16+lr)*128 + co];
                __builtin_amdgcn_s_setprio(1);
                #pragma unroll
                for (int mt=0;mt<4;mt++)
                    #pragma unroll
                    for (int nt=0;nt<4;nt++)
                        acc[mt][nt] = __builtin_amdgcn_mfma_f32_16x16x32_bf16(af[mt], bf[nt], acc[mt][nt], 0,0,0);
                __builtin_amdgcn_s_setprio(0);
            }
        }

        // ---- packed epilogue: fold bias -> bf16 -> LDS (stride 132) -> 16B stores ----
        __syncthreads();    // all waves done reading As/Bs
        #pragma unroll
        for (int mt=0;mt<4;mt++)
            #pragma unroll
            for (int r=0;r<4;r++){
                int row = wr*64 + mt*16 + g*4 + r;
                #pragma unroll
                for (int nt=0;nt<4;nt++){
                    int col = wc*64 + nt*16 + lr;
                    lds[row*132 + col] = f2b((acc[mt][nt][r] + addf[nt]) * sclf[nt]);
                }
            }
        __syncthreads();
        const us* outp = (EPI == 0) ? (whc == 0 ? Qo : (whc == 1 ? Ko : Vo)) : nullptr;
        #pragma unroll
        for (int j=0;j<8;j++){
            int c2  = tid + j*256;
            int row = c2 >> 4;
            int ch  = c2 & 15;
            int m = m0 + row;
            if (m >= MTOT) continue;
            short8 vv = *(const short8*)&lds[row*132 + ch*8];
            if (EPI == 1){
                int n = n0 + ch*8;
                float4 f0, f1;
                f0.x = b2f((us)vv[0]); f0.y = b2f((us)vv[1]); f0.z = b2f((us)vv[2]); f0.w = b2f((us)vv[3]);
                f1.x = b2f((us)vv[4]); f1.y = b2f((us)vv[5]); f1.z = b2f((us)vv[6]); f1.w = b2f((us)vv[7]);
                *(float4*)&Cout[(size_t)m*CDIM + n]     = f0;
                *(float4*)&Cout[(size_t)m*CDIM + n + 4] = f1;
            } else {
                int n  = n0 + ch*8;
                int hn = n - whc*CDIM;
                int h  = hn >> 6, d0 = hn & 63;
                int bidx = m / NTOK;
                int tok  = m - bidx*NTOK;
                size_t off = ((size_t)((bidx*NH + h)*NTOK + tok))*HD + d0;
                *(short8*)((us*)outp + off) = vv;
            }
        }
        // next tile's first __syncthreads() protects LDS reuse
    }
}

// ---------------- fused attention: one block per (b,h) ----------------
__global__ __launch_bounds__(256) void attn_kernel(
    const us* __restrict__ Q,
    const us* __restrict__ K,
    const us* __restrict__ V,
    const float* __restrict__ biasm,
    us* __restrict__ Ao)
{
    __shared__ us Vt[64][232];
    __shared__ us Ps[4][16][232];
    const int bh = blockIdx.x;
    const int b = bh / NH;
    const int h = bh - b*NH;
    const us* Qh = Q + (size_t)bh*NTOK*HD;
    const us* Kh = K + (size_t)bh*NTOK*HD;
    const us* Vh = V + (size_t)bh*NTOK*HD;
    const float* bh_bias = biasm + (size_t)h*NTOK*NTOK;
    const int tid = threadIdx.x, lane = tid & 63, wave = tid >> 6;
    const int lr = lane & 15, g = lane >> 4, ko = g*8;

    for (int i = tid; i < 64*232/2; i += 256) ((uint32_t*)Vt)[i] = 0;
    __syncthreads();
    {
        int d0 = (tid & 7) * 8;
        for (int t = tid >> 3; t < NTOK; t += 32){
            short8 v = *(const short8*)&Vh[t*HD + d0];
            #pragma unroll
            for (int j=0;j<8;j++) Vt[d0+j][t] = (us)v[j];
        }
    }
    __syncthreads();

    for (int s = wave; s < 13; s += 4){
        int qrow = s*16 + lr; qrow = qrow > 196 ? 196 : qrow;
        short8 qa0 = *(const short8*)&Qh[qrow*HD + ko];
        short8 qa1 = *(const short8*)&Qh[qrow*HD + 32 + ko];
        f32x4 S[13];
        #pragma unroll
        for (int t=0;t<13;t++){
            int kc = t*16 + lr; kc = kc > 196 ? 196 : kc;
            short8 kb0 = *(const short8*)&Kh[kc*HD + ko];
            short8 kb1 = *(const short8*)&Kh[kc*HD + 32 + ko];
            f32x4 a = (f32x4){0.f,0.f,0.f,0.f};
            a = __builtin_amdgcn_mfma_f32_16x16x32_bf16(qa0, kb0, a, 0,0,0);
            a = __builtin_amdgcn_mfma_f32_16x16x32_bf16(qa1, kb1, a, 0,0,0);
            S[t] = a;
        }
        float rmax[4] = {-3e38f,-3e38f,-3e38f,-3e38f};
        #pragma unroll
        for (int t=0;t<13;t++){
            int col = t*16 + lr;
            bool cok = col < NTOK;
            int colc = cok ? col : 196;
            #pragma unroll
            for (int r=0;r<4;r++){
                int row = s*16 + g*4 + r; row = row > 196 ? 196 : row;
                float xv = S[t][r] + bh_bias[row*NTOK + colc];
                xv = cok ? xv : -1e30f;
                S[t][r] = xv;
                rmax[r] = fmaxf(rmax[r], xv);
            }
        }
        #pragma unroll
        for (int r=0;r<4;r++)
            #pragma unroll
            for (int msk=1; msk<16; msk<<=1)
                rmax[r] = fmaxf(rmax[r], __shfl_xor(rmax[r], msk));
        float rsum[4] = {0.f,0.f,0.f,0.f};
        #pragma unroll
        for (int t=0;t<13;t++)
            #pragma unroll
            for (int r=0;r<4;r++){
                float e = __expf(S[t][r] - rmax[r]);
                S[t][r] = e;
                rsum[r] += e;
            }
        #pragma unroll
        for (int r=0;r<4;r++){
            #pragma unroll
            for (int msk=1; msk<16; msk<<=1)
                rsum[r] += __shfl_xor(rsum[r], msk);
            rsum[r] = 1.f / rsum[r];
        }
        #pragma unroll
        for (int t=0;t<13;t++)
            #pragma unroll
            for (int r=0;r<4;r++)
                Ps[wave][g*4+r][t*16+lr] = f2b(S[t][r] * rsum[r]);
        #pragma unroll
        for (int r=0;r<4;r++) Ps[wave][g*4+r][208+lr] = 0;
        asm volatile("s_waitcnt lgkmcnt(0)" ::: "memory");
        f32x4 pv[4];
        #pragma unroll
        for (int nt=0;nt<4;nt++) pv[nt] = (f32x4){0.f,0.f,0.f,0.f};
        #pragma unroll
        for (int ks=0; ks<7; ks++){
            int k0 = ks*32 + ko;
            short8 pa = *(const short8*)&Ps[wave][lr][k0];
            #pragma unroll
            for (int nt=0;nt<4;nt++){
                short8 vb = *(const short8*)&Vt[nt*16+lr][k0];
                pv[nt] = __builtin_amdgcn_mfma_f32_16x16x32_bf16(pa, vb, pv[nt], 0,0,0);
            }
        }
        #pragma unroll
        for (int nt=0;nt<4;nt++)
            #pragma unroll
            for (int r=0;r<4;r++){
                int tok = s*16 + g*4 + r;
                if (tok < NTOK)
                    Ao[(size_t)(b*NTOK + tok)*CDIM + h*HD + nt*16 + lr] = f2b(pv[nt][r]);
            }
    }
}

extern "C" void kernel_launch(void* const* d_in, const int* in_sizes, int n_in,
                              void* d_out, int out_size, void* d_ws, size_t ws_size,
                              hipStream_t stream)
{
    const float* x        = (const float*)d_in[0];
    const float* qkv_w    = (const float*)d_in[1];
    const float* q_bias   = (const float*)d_in[2];
    const float* v_bias   = (const float*)d_in[3];
    const float* rel_tab  = (const float*)d_in[4];
    const float* proj_w   = (const float*)d_in[5];
    const float* proj_b   = (const float*)d_in[6];
    const int*   rel_idx  = (const int*)d_in[7];
    float* out = (float*)d_out;

    char* w = (char*)d_ws;
    us* xb    = (us*)w; w += (size_t)MPAD*CDIM*2;
    us* wqkv  = (us*)w; w += (size_t)3*CDIM*CDIM*2;
    us* wproj = (us*)w; w += (size_t)CDIM*CDIM*2;
    us* Qb    = (us*)w; w += (size_t)BB*NH*NTOK*HD*2;
    us* Kb    = (us*)w; w += (size_t)BB*NH*NTOK*HD*2;
    us* Vb    = (us*)w; w += (size_t)BB*NH*NTOK*HD*2;
    float* biasm = (float*)w; w += (size_t)NH*NTOK*NTOK*4;
    us* aob   = (us*)w; w += (size_t)MPAD*CDIM*2;

    int n1 = MTOT*CDIM/4;
    cvt_kernel<<<(n1+255)/256, 256, 0, stream>>>(x, xb, n1);
    int n2 = 3*CDIM*CDIM/4;
    cvt_kernel<<<(n2+255)/256, 256, 0, stream>>>(qkv_w, wqkv, n2);
    int n3 = CDIM*CDIM/4;
    cvt_kernel<<<(n3+255)/256, 256, 0, stream>>>(proj_w, wproj, n3);
    bias_kernel<<<(NTOK*NTOK+255)/256, 256, 0, stream>>>(rel_idx, rel_tab, biasm);

    // QKV: 99 x 18 = 1782 tiles, 594 persistent blocks x 3 tiles (same A panel)
    pgemm_kernel<0,3><<<594, 256, 0, stream>>>(xb, wqkv, nullptr, Qb, Kb, Vb, q_bias, v_bias, 18);
    attn_kernel<<<BB*NH, 256, 0, stream>>>(Qb, Kb, Vb, biasm, aob);
    // proj: 99 x 6 = 594 tiles, 594 blocks x 1 tile
    pgemm_kernel<1,1><<<594, 256, 0, stream>>>(aob, wproj, out, nullptr, nullptr, nullptr, proj_b, nullptr, 6);
}